// Round 8
// baseline (394.607 us; speedup 1.0000x reference)
//
#include <hip/hip_runtime.h>
#include <math.h>

// ---------------------------------------------------------------------------
// cross_scale_attention v8: full-row GEMM1 + fused softmax, full-M GEMM2
//   qps[n][f][385][97][64] f16 <- conv3(pan, wq, bq), phase-split x (f=x'&3)
//   kcl[n][96][96][64]   f16 <- conv3(pan2, wk, bk), channels-last
//   v_fea fp32           <- conv3(ms, wv, bv)
//   Kmat[n][576][(kh,kw,c)] f16 + norms  <- kcl gather  (no pad rows)
//   Vt[n][256][576] f16 (rows >=200 zero)
//   csa_gemm1s: block = 64p x 576l x BK32. A (qps) fetched ONCE (was 5x);
//       Kmat (2MB/batch) L2-resident. Epilogue: exact softmax in-reg +
//       cross-wave LDS reduce -> attnT[n][p][l] f16 normalized.
//   csa_gemm2: block = 256m x 64p x BK64; attnT fetched once, Vt L2-hot.
//       -> D[n][m][p] f16
//   res = gather(D)/6 f32 ; out = lrelu(conv3(res, wr, br))
// ---------------------------------------------------------------------------

typedef _Float16 f16;
typedef _Float16 f16x8 __attribute__((ext_vector_type(8)));
typedef float f32x4 __attribute__((ext_vector_type(4)));

namespace csa {
constexpr int NB   = 2;
constexpr int MID  = 64;
constexpr int BAND = 8;
constexpr int HK   = 96;
constexpr int HQ   = 384;
constexpr int HQP  = 385;
constexpr int XI   = 97;
constexpr int LN   = 24;
constexpr int L    = 576;
constexpr int PS   = 96 * 96;       // 9216
constexpr int KDIM = MID * 25;      // 1600
constexpr int VDIM = BAND * 25;     // 200
constexpr int MV   = 256;
constexpr int HO   = 385;
constexpr size_t QPSN = (size_t)4 * HQP * XI * MID;

constexpr size_t align256(size_t x) { return (x + 255) & ~(size_t)255; }
constexpr size_t OFF_QPS  = 0;                                            // f16
constexpr size_t OFF_KCL  = align256(OFF_QPS + (size_t)NB*QPSN*2);        // f16
constexpr size_t OFF_VFEA = align256(OFF_KCL + (size_t)NB*HK*HK*MID*2);   // f32
constexpr size_t OFF_N2   = align256(OFF_VFEA + (size_t)NB*BAND*HK*HK*4);
constexpr size_t OFF_SC   = align256(OFF_N2   + (size_t)NB*L*4);
constexpr size_t OFF_KM   = align256(OFF_SC   + 256);                     // f16 NB*576*1600
constexpr size_t OFF_VT   = align256(OFF_KM   + (size_t)NB*L*KDIM*2);     // f16 NB*256*576
constexpr size_t OFF_AT   = align256(OFF_VT   + (size_t)NB*MV*L*2);       // f16 NB*9216*576
constexpr size_t OFF_D    = align256(OFF_AT   + (size_t)NB*PS*L*2);       // f16 NB*256*9216
constexpr size_t OFF_RES  = align256(OFF_D    + (size_t)NB*MV*PS*2);      // f32 NB*8*385*385
}  // namespace csa
using namespace csa;

// -------- conv3 1->64 channels-last f16, phase-split output for q -----------
__global__ __launch_bounds__(256) void csa_convq_ps(
    const float* __restrict__ in, const float* __restrict__ w,
    const float* __restrict__ b, f16* __restrict__ out) {
  int id = blockIdx.x * 256 + threadIdx.x;
  int total = NB * 4 * HQP * XI;
  if (id >= total) return;
  int xi = id % XI;
  int t = id / XI;
  int yp = t % HQP;
  t /= HQP;
  int f = t % 4;
  int n = t / 4;
  int xp = 4 * xi + f;
  f16* op = out + (size_t)id * MID;
  if (yp >= HQ || xp >= HQ) {
    f16x8 z = {0, 0, 0, 0, 0, 0, 0, 0};
#pragma unroll
    for (int c8 = 0; c8 < 8; ++c8) *(f16x8*)(op + c8 * 8) = z;
    return;
  }
  const float* ip = in + (size_t)n * HQ * HQ;
  float p[9];
#pragma unroll
  for (int dy = 0; dy < 3; ++dy)
#pragma unroll
    for (int dx = 0; dx < 3; ++dx) {
      int yy = yp + dy - 1, xx = xp + dx - 1;
      p[dy * 3 + dx] = (yy >= 0 && yy < HQ && xx >= 0 && xx < HQ)
                           ? ip[(size_t)yy * HQ + xx] : 0.f;
    }
#pragma unroll
  for (int c8 = 0; c8 < 8; ++c8) {
    f16x8 o;
#pragma unroll
    for (int e = 0; e < 8; ++e) {
      int co = c8 * 8 + e;
      float acc = b[co];
#pragma unroll
      for (int k = 0; k < 9; ++k) acc = fmaf(p[k], w[co * 9 + k], acc);
      o[e] = (f16)(acc > 0.f ? acc : 0.01f * acc);
    }
    *(f16x8*)(op + c8 * 8) = o;
  }
}

// ---------- conv3 1->64, channels-last f16 out (for k features) -------------
__global__ __launch_bounds__(256) void csa_conv_cl(
    const float* __restrict__ in, const float* __restrict__ w,
    const float* __restrict__ b, f16* __restrict__ out, int H) {
  int id = blockIdx.x * 256 + threadIdx.x;
  int total = NB * H * H;
  if (id >= total) return;
  int x = id % H;
  int t = id / H;
  int y = t % H;
  int n = t / H;
  f16* op = out + (size_t)id * MID;
  const float* ip = in + (size_t)n * H * H;
  float p[9];
#pragma unroll
  for (int dy = 0; dy < 3; ++dy)
#pragma unroll
    for (int dx = 0; dx < 3; ++dx) {
      int yy = y + dy - 1, xx = x + dx - 1;
      p[dy * 3 + dx] = (yy >= 0 && yy < H && xx >= 0 && xx < H)
                           ? ip[(size_t)yy * H + xx] : 0.f;
    }
#pragma unroll
  for (int c8 = 0; c8 < 8; ++c8) {
    f16x8 o;
#pragma unroll
    for (int e = 0; e < 8; ++e) {
      int co = c8 * 8 + e;
      float acc = b[co];
#pragma unroll
      for (int k = 0; k < 9; ++k) acc = fmaf(p[k], w[co * 9 + k], acc);
      o[e] = (f16)(acc > 0.f ? acc : 0.01f * acc);
    }
    *(f16x8*)(op + c8 * 8) = o;
  }
}

// ------------------------- conv3: 8 in-ch -> 8 out-ch -----------------------
__global__ __launch_bounds__(256) void csa_conv3_8x8(
    const float* __restrict__ in, const float* __restrict__ w,
    const float* __restrict__ b, float* __restrict__ out, int H, int W) {
  int id = blockIdx.x * 256 + threadIdx.x;
  int total = NB * H * W;
  if (id >= total) return;
  int x = id % W;
  int t = id / W;
  int y = t % H;
  int n = t / H;
  const float* ip = in + (size_t)n * BAND * H * W;
  float p[BAND][9];
#pragma unroll
  for (int ci = 0; ci < BAND; ++ci)
#pragma unroll
    for (int dy = 0; dy < 3; ++dy)
#pragma unroll
      for (int dx = 0; dx < 3; ++dx) {
        int yy = y + dy - 1, xx = x + dx - 1;
        p[ci][dy * 3 + dx] = (yy >= 0 && yy < H && xx >= 0 && xx < W)
                                 ? ip[((size_t)ci * H + yy) * W + xx] : 0.f;
      }
  float* op = out + ((size_t)n * BAND * H + y) * W + x;
  for (int co = 0; co < BAND; ++co) {
    float acc = b[co];
#pragma unroll
    for (int ci = 0; ci < BAND; ++ci)
#pragma unroll
      for (int k = 0; k < 9; ++k)
        acc = fmaf(p[ci][k], w[(co * BAND + ci) * 9 + k], acc);
    acc = acc > 0.f ? acc : 0.01f * acc;
    op[(size_t)co * H * W] = acc;
  }
}

// ---- patches: Kmat[l][(kh,kw,c)] f16 (576 rows), Vt[m][l], norms² ----------
__global__ __launch_bounds__(256) void csa_build_patches(
    const f16* __restrict__ kcl, const float* __restrict__ v_fea,
    f16* __restrict__ Kmat, f16* __restrict__ Vt, float* __restrict__ n2) {
  int blk = blockIdx.x;  // NB*L blocks
  int n = blk / L;
  int l = blk % L;
  int tid = threadIdx.x;
  f16* krow = Kmat + ((size_t)n * L + l) * KDIM;
  int i = l / LN, j = l % LN;
  const f16* kn = kcl + (size_t)n * HK * HK * MID;
  float ss = 0.f;
  for (int ch = tid; ch < 200; ch += 256) {
    int khkw = ch >> 3;
    int c0 = (ch & 7) * 8;
    int kh = khkw / 5, kw = khkw % 5;
    int r = (4 * i + kh + 95) % 97;
    int cc = (4 * j + kw + 95) % 97;
    f16x8 v = {0, 0, 0, 0, 0, 0, 0, 0};
    if (r < HK && cc < HK)
      v = *(const f16x8*)(kn + ((size_t)r * HK + cc) * MID + c0);
#pragma unroll
    for (int e = 0; e < 8; ++e) {
      float fv = (float)v[e];
      ss += fv * fv;
    }
    *(f16x8*)(krow + ch * 8) = v;
  }
  for (int m = tid; m < MV; m += 256) {
    float v = 0.f;
    if (m < VDIM) {
      int kw = m % 5;
      int t = m / 5;
      int kh = t % 5;
      int c = t / 5;
      int r = (4 * i + kh + 95) % 97;
      int cc = (4 * j + kw + 95) % 97;
      v = (r < HK && cc < HK)
              ? v_fea[(((size_t)n * BAND + c) * HK + r) * HK + cc] : 0.f;
    }
    Vt[((size_t)n * MV + m) * L + l] = (f16)v;
  }
  __shared__ float red[256];
  red[tid] = ss;
  __syncthreads();
  for (int s = 128; s > 0; s >>= 1) {
    if (tid < s) red[tid] += red[tid + s];
    __syncthreads();
  }
  if (tid == 0) n2[n * L + l] = red[0];
}

// ---------------- scale[n] = 10 / sqrt(max_l norms2[n][l]) ------------------
__global__ __launch_bounds__(256) void csa_max_scale(
    const float* __restrict__ n2, float* __restrict__ scale) {
  int n = blockIdx.x;
  int tid = threadIdx.x;
  float m = 0.f;
  for (int l = tid; l < L; l += 256) m = fmaxf(m, n2[n * L + l]);
  __shared__ float red[256];
  red[tid] = m;
  __syncthreads();
  for (int s = 128; s > 0; s >>= 1) {
    if (tid < s) red[tid] = fmaxf(red[tid], red[tid + s]);
    __syncthreads();
  }
  if (tid == 0) scale[n] = 10.f / sqrtf(red[0]);
}

// --------------------------- MFMA GEMM helpers ------------------------------
__device__ __forceinline__ void gl_lds16(const f16* g, f16* s) {
  __builtin_amdgcn_global_load_lds(
      (const __attribute__((address_space(1))) void*)g,
      (__attribute__((address_space(3))) void*)s, 16, 0, 0);
}

// ------ GEMM1 + softmax: attnT[p][l] = softmax_l(Q x K^T * sc) --------------
// Block: 64p x 576l, BK=32, 50 rounds. A staged once (1 call/round), B 9
// calls/round (Kmat 2MB/batch -> L2). Each wave: all 4 m-tiles x 9 n-tiles
// (acc 144 VGPR); per wave per round 13 ds_read_b128 vs 36 MFMA.
// Epilogue: exact row softmax (in-reg + LDS cross-wave), writes attnT f16.
__global__ __launch_bounds__(256) void csa_gemm1s(
    const f16* __restrict__ qps, const f16* __restrict__ Km,
    const float* __restrict__ scale, f16* __restrict__ attnT) {
  __shared__ __attribute__((aligned(16))) f16 As[4 * 512];    // 64 x 32
  __shared__ __attribute__((aligned(16))) f16 Bs[36 * 512];   // 576 x 32
  __shared__ float mt[4][64], st[4][64], mrow[64], linv[64];

  const int tid = threadIdx.x;
  const int w = tid >> 6;
  const int lane = tid & 63;
  const int q = lane >> 4;
  const int r = lane & 15;
  const int nb = blockIdx.y;
  const int bp = blockIdx.x * 64;
  const float sc = scale[nb];
  qps += (size_t)nb * QPSN;
  Km += (size_t)nb * (size_t)L * KDIM;
  f16* at = attnT + (size_t)nb * PS * L;

  // A staging: 1 call/round; thread stages tile w, row r, 8 chans at q*8.
  const int pA = bp + 16 * w + r;
  const int yA = pA / 96, xA = pA % 96;
  const size_t laneA = ((size_t)(4 * yA) * XI + xA) * MID + q * 8;
  // B staging: 9 calls; call c stages tile 4c+w: row l=64c+16w+r, k=k0+q*8.
  const f16* KmB = Km + (size_t)(16 * w + r) * KDIM + q * 8;

  f32x4 acc[4][9];
#pragma unroll
  for (int i = 0; i < 4; ++i)
#pragma unroll
    for (int j = 0; j < 9; ++j) {
      f32x4 z = {0.f, 0.f, 0.f, 0.f};
      acc[i][j] = z;
    }

  for (int k0 = 0; k0 < KDIM; k0 += 32) {
    const int t32 = k0 >> 5;
    const int half = t32 & 1;
    const int khkw = t32 >> 1;
    const int kh = khkw / 5, kw = khkw % 5;
    const size_t roundA = (((size_t)(kw & 3) * HQP + kh) * XI + (kw >> 2)) * MID +
                          half * 32;
    gl_lds16(qps + roundA + laneA, As + w * 512);
#pragma unroll
    for (int c = 0; c < 9; ++c)
      gl_lds16(KmB + (size_t)(64 * c) * KDIM + k0, Bs + (c * 4 + w) * 512);
    __syncthreads();
    f16x8 af[4];
#pragma unroll
    for (int i = 0; i < 4; ++i)
      af[i] = *(const f16x8*)&As[i * 512 + q * 128 + r * 8];
#pragma unroll
    for (int j = 0; j < 9; ++j) {
      f16x8 bf = *(const f16x8*)&Bs[(w * 9 + j) * 512 + q * 128 + r * 8];
#pragma unroll
      for (int i = 0; i < 4; ++i)
        acc[i][j] =
            __builtin_amdgcn_mfma_f32_16x16x32_f16(af[i], bf, acc[i][j], 0, 0, 0);
    }
    __syncthreads();
  }

  // ---- exact softmax over l; lane holds rows 16i+4q+rr, cols 144w+16j+r ----
#pragma unroll
  for (int i = 0; i < 4; ++i)
#pragma unroll
    for (int rr = 0; rr < 4; ++rr) {
      float mx = -1e30f;
#pragma unroll
      for (int j = 0; j < 9; ++j) mx = fmaxf(mx, acc[i][j][rr]);
      mx = fmaxf(mx, __shfl_xor(mx, 1));
      mx = fmaxf(mx, __shfl_xor(mx, 2));
      mx = fmaxf(mx, __shfl_xor(mx, 4));
      mx = fmaxf(mx, __shfl_xor(mx, 8));
      if (r == 0) mt[w][16 * i + 4 * q + rr] = mx;
    }
  __syncthreads();
  if (tid < 64)
    mrow[tid] = fmaxf(fmaxf(mt[0][tid], mt[1][tid]),
                      fmaxf(mt[2][tid], mt[3][tid]));
  __syncthreads();
#pragma unroll
  for (int i = 0; i < 4; ++i)
#pragma unroll
    for (int rr = 0; rr < 4; ++rr) {
      const float m = mrow[16 * i + 4 * q + rr];
      float s = 0.f;
#pragma unroll
      for (int j = 0; j < 9; ++j) {
        float e = __expf((acc[i][j][rr] - m) * sc);
        acc[i][j][rr] = e;
        s += e;
      }
      s += __shfl_xor(s, 1);
      s += __shfl_xor(s, 2);
      s += __shfl_xor(s, 4);
      s += __shfl_xor(s, 8);
      if (r == 0) st[w][16 * i + 4 * q + rr] = s;
    }
  __syncthreads();
  if (tid < 64)
    linv[tid] = 1.f / (st[0][tid] + st[1][tid] + st[2][tid] + st[3][tid]);
  __syncthreads();
#pragma unroll
  for (int i = 0; i < 4; ++i)
#pragma unroll
    for (int rr = 0; rr < 4; ++rr) {
      const int row = 16 * i + 4 * q + rr;
      const float li = linv[row];
      f16* orow = at + (size_t)(bp + row) * L + 144 * w + r;
#pragma unroll
      for (int j = 0; j < 9; ++j) orow[16 * j] = (f16)(acc[i][j][rr] * li);
    }
}

// ------ GEMM2: D[m][p] f16 = Vt[256][576] x attnT[p][576]^T -----------------
// Block: 256m x 64p, BK=64, 9 rounds. attnT fetched once; Vt L2-hot.
__global__ __launch_bounds__(256) void csa_gemm2(
    const f16* __restrict__ Vt, const f16* __restrict__ attnT,
    f16* __restrict__ D) {
  __shared__ __attribute__((aligned(16))) f16 As[16 * 1024];  // 256 x 64
  __shared__ __attribute__((aligned(16))) f16 Bs[4 * 1024];   // 64 x 64
  const int tid = threadIdx.x;
  const int w = tid >> 6;
  const int lane = tid & 63;
  const int q = lane >> 4;
  const int r = lane & 15;
  const int nb = blockIdx.y;
  const int bn = blockIdx.x * 64;
  Vt += (size_t)nb * MV * L;
  attnT += (size_t)nb * (size_t)PS * L;
  D += (size_t)nb * (size_t)MV * PS;

  f32x4 acc[4][4];
#pragma unroll
  for (int i = 0; i < 4; ++i)
#pragma unroll
    for (int j = 0; j < 4; ++j) {
      f32x4 z = {0.f, 0.f, 0.f, 0.f};
      acc[i][j] = z;
    }

  const int tA = w >> 1;   // 0/1: tile parity within call
  const int kkA = w & 1;   // k-half within call
  const f16* gA = Vt + (size_t)(16 * tA + r) * L + kkA * 32 + q * 8;
  const f16* gB = attnT + (size_t)(bn + 16 * tA + r) * L + kkA * 32 + q * 8;

  for (int k0 = 0; k0 < L; k0 += 64) {
#pragma unroll
    for (int c = 0; c < 8; ++c)
      gl_lds16(gA + (size_t)(32 * c) * L + k0,
               As + (2 * c + tA) * 1024 + kkA * 512);
#pragma unroll
    for (int c = 0; c < 2; ++c)
      gl_lds16(gB + (size_t)(32 * c) * L + k0,
               Bs + (2 * c + tA) * 1024 + kkA * 512);
    __syncthreads();
#pragma unroll
    for (int kk = 0; kk < 2; ++kk) {
      f16x8 af[4], bf[4];
#pragma unroll
      for (int i = 0; i < 4; ++i)
        af[i] =
            *(const f16x8*)&As[(4 * w + i) * 1024 + kk * 512 + q * 128 + r * 8];
#pragma unroll
      for (int j = 0; j < 4; ++j)
        bf[j] = *(const f16x8*)&Bs[j * 1024 + kk * 512 + q * 128 + r * 8];
#pragma unroll
      for (int i = 0; i < 4; ++i)
#pragma unroll
        for (int j = 0; j < 4; ++j)
          acc[i][j] = __builtin_amdgcn_mfma_f32_16x16x32_f16(af[i], bf[j],
                                                             acc[i][j], 0, 0, 0);
    }
    __syncthreads();
  }
#pragma unroll
  for (int i = 0; i < 4; ++i)
#pragma unroll
    for (int j = 0; j < 4; ++j)
#pragma unroll
      for (int rr = 0; rr < 4; ++rr)
        D[(size_t)(64 * w + 16 * i + 4 * q + rr) * PS + bn + 16 * j + r] =
            (f16)acc[i][j][rr];
}

// ------ conv_transpose overlap gather: res[n][co][oy][ox] = sum D / 6 -------
__global__ __launch_bounds__(256) void csa_gather(
    const f16* __restrict__ D, float* __restrict__ res) {
  int id = blockIdx.x * 256 + threadIdx.x;
  if (id >= NB * BAND * HO * HO) return;
  int ox = id % HO;
  int t = id / HO;
  int oy = t % HO;
  t = t / HO;
  int co = t % BAND;
  int n = t / BAND;
  const f16* Dn = D + (size_t)n * MV * PS;
  float s = 0.f;
  int kh0 = oy & 3;
  int kw0 = ox & 3;
  for (int kh = kh0; kh < 5; kh += 4) {
    int y = (oy - kh) >> 2;
    if (y < 0 || y >= 96) continue;
    for (int kw = kw0; kw < 5; kw += 4) {
      int x = (ox - kw) >> 2;
      if (x < 0 || x >= 96) continue;
      s += (float)Dn[(size_t)(co * 25 + kh * 5 + kw) * PS + y * 96 + x];
    }
  }
  res[id] = s * (1.f / 6.f);
}

// ---------------------------------------------------------------------------
extern "C" void kernel_launch(void* const* d_in, const int* in_sizes, int n_in,
                              void* d_out, int out_size, void* d_ws,
                              size_t ws_size, hipStream_t stream) {
  const float* ms   = (const float*)d_in[0];
  const float* pan  = (const float*)d_in[1];
  const float* pan2 = (const float*)d_in[2];
  const float* wq = (const float*)d_in[3];
  const float* bq = (const float*)d_in[4];
  const float* wk = (const float*)d_in[5];
  const float* bk = (const float*)d_in[6];
  const float* wv = (const float*)d_in[7];
  const float* bv = (const float*)d_in[8];
  const float* wr = (const float*)d_in[9];
  const float* br = (const float*)d_in[10];
  float* out = (float*)d_out;

  char* ws = (char*)d_ws;
  f16*   qps   = (f16*)(ws + OFF_QPS);
  f16*   kcl   = (f16*)(ws + OFF_KCL);
  float* v_fea = (float*)(ws + OFF_VFEA);
  float* n2    = (float*)(ws + OFF_N2);
  float* scale = (float*)(ws + OFF_SC);
  f16*   Kmat  = (f16*)(ws + OFF_KM);
  f16*   Vt    = (f16*)(ws + OFF_VT);
  f16*   attnT = (f16*)(ws + OFF_AT);
  f16*   Dm    = (f16*)(ws + OFF_D);
  float* res   = (float*)(ws + OFF_RES);

  dim3 b256(256);
  csa_convq_ps<<<dim3((NB * 4 * HQP * XI + 255) / 256), b256, 0, stream>>>(
      pan, wq, bq, qps);
  csa_conv_cl<<<dim3((NB * HK * HK + 255) / 256), b256, 0, stream>>>(
      pan2, wk, bk, kcl, HK);
  csa_conv3_8x8<<<dim3((NB * HK * HK + 255) / 256), b256, 0, stream>>>(
      ms, wv, bv, v_fea, HK, HK);
  csa_build_patches<<<dim3(NB * L), b256, 0, stream>>>(kcl, v_fea, Kmat, Vt,
                                                       n2);
  csa_max_scale<<<dim3(NB), b256, 0, stream>>>(n2, scale);

  // fused GEMM1 + softmax -> attnT
  csa_gemm1s<<<dim3(PS / 64, NB), b256, 0, stream>>>(qps, Kmat, scale, attnT);

  // GEMM2 -> D f16
  csa_gemm2<<<dim3(PS / 64, NB), b256, 0, stream>>>(Vt, attnT, Dm);

  csa_gather<<<dim3((NB * BAND * HO * HO + 255) / 256), b256, 0, stream>>>(
      Dm, res);
  csa_conv3_8x8<<<dim3((NB * HO * HO + 255) / 256), b256, 0, stream>>>(
      res, wr, br, out, HO, HO);
}

// Round 9
// 380.948 us; speedup vs baseline: 1.0359x; 1.0359x over previous
//
#include <hip/hip_runtime.h>
#include <math.h>

// ---------------------------------------------------------------------------
// cross_scale_attention v9: fused attention, BM=32 full-row tile
//   qps[n][f][385][97][64] f16 <- conv3(pan, wq, bq), phase-split x (f=x'&3)
//   kcl[n][96][96][64]   f16 <- conv3(pan2, wk, bk), channels-last
//   v_fea fp32           <- conv3(ms, wv, bv)
//   Kmat[n][576][(kh,kw,c)] f16 + norms  <- kcl gather
//   Vt[n][256][576] f16 (rows >=200 zero)
//   csa_attn (576 blocks): 32p x 576l x BK32, LDS-staged A/B (coalesced,
//       wave-granular tiles); S rows complete in regs -> exact softmax
//       (in-reg + LDS cross-wave); e^x f16 -> reused LDS; PV with direct
//       L2-hot Vt loads -> D[n][256][9216] f16 (normalize at write).
//   res = gather(D)/6 f32 ; out = lrelu(conv3(res, wr, br))
// ---------------------------------------------------------------------------

typedef _Float16 f16;
typedef _Float16 f16x8 __attribute__((ext_vector_type(8)));
typedef float f32x4 __attribute__((ext_vector_type(4)));

namespace csa {
constexpr int NB   = 2;
constexpr int MID  = 64;
constexpr int BAND = 8;
constexpr int HK   = 96;
constexpr int HQ   = 384;
constexpr int HQP  = 385;
constexpr int XI   = 97;
constexpr int LN   = 24;
constexpr int L    = 576;
constexpr int PS   = 96 * 96;       // 9216
constexpr int KDIM = MID * 25;      // 1600
constexpr int VDIM = BAND * 25;     // 200
constexpr int MV   = 256;
constexpr int HO   = 385;
constexpr int PADL = 584;           // attn LDS row stride f16 (2-way banks)
constexpr size_t QPSN = (size_t)4 * HQP * XI * MID;

constexpr size_t align256(size_t x) { return (x + 255) & ~(size_t)255; }
constexpr size_t OFF_QPS  = 0;                                            // f16
constexpr size_t OFF_KCL  = align256(OFF_QPS + (size_t)NB*QPSN*2);        // f16
constexpr size_t OFF_VFEA = align256(OFF_KCL + (size_t)NB*HK*HK*MID*2);   // f32
constexpr size_t OFF_N2   = align256(OFF_VFEA + (size_t)NB*BAND*HK*HK*4);
constexpr size_t OFF_SC   = align256(OFF_N2   + (size_t)NB*L*4);
constexpr size_t OFF_KM   = align256(OFF_SC   + 256);                     // f16 NB*576*1600
constexpr size_t OFF_VT   = align256(OFF_KM   + (size_t)NB*L*KDIM*2);     // f16 NB*256*576
constexpr size_t OFF_D    = align256(OFF_VT   + (size_t)NB*MV*L*2);       // f16 NB*256*9216
constexpr size_t OFF_RES  = align256(OFF_D    + (size_t)NB*MV*PS*2);      // f32 NB*8*385*385
}  // namespace csa
using namespace csa;

// -------- conv3 1->64 channels-last f16, phase-split output for q -----------
__global__ __launch_bounds__(256) void csa_convq_ps(
    const float* __restrict__ in, const float* __restrict__ w,
    const float* __restrict__ b, f16* __restrict__ out) {
  int id = blockIdx.x * 256 + threadIdx.x;
  int total = NB * 4 * HQP * XI;
  if (id >= total) return;
  int xi = id % XI;
  int t = id / XI;
  int yp = t % HQP;
  t /= HQP;
  int f = t % 4;
  int n = t / 4;
  int xp = 4 * xi + f;
  f16* op = out + (size_t)id * MID;
  if (yp >= HQ || xp >= HQ) {
    f16x8 z = {0, 0, 0, 0, 0, 0, 0, 0};
#pragma unroll
    for (int c8 = 0; c8 < 8; ++c8) *(f16x8*)(op + c8 * 8) = z;
    return;
  }
  const float* ip = in + (size_t)n * HQ * HQ;
  float p[9];
#pragma unroll
  for (int dy = 0; dy < 3; ++dy)
#pragma unroll
    for (int dx = 0; dx < 3; ++dx) {
      int yy = yp + dy - 1, xx = xp + dx - 1;
      p[dy * 3 + dx] = (yy >= 0 && yy < HQ && xx >= 0 && xx < HQ)
                           ? ip[(size_t)yy * HQ + xx] : 0.f;
    }
#pragma unroll
  for (int c8 = 0; c8 < 8; ++c8) {
    f16x8 o;
#pragma unroll
    for (int e = 0; e < 8; ++e) {
      int co = c8 * 8 + e;
      float acc = b[co];
#pragma unroll
      for (int k = 0; k < 9; ++k) acc = fmaf(p[k], w[co * 9 + k], acc);
      o[e] = (f16)(acc > 0.f ? acc : 0.01f * acc);
    }
    *(f16x8*)(op + c8 * 8) = o;
  }
}

// ---------- conv3 1->64, channels-last f16 out (for k features) -------------
__global__ __launch_bounds__(256) void csa_conv_cl(
    const float* __restrict__ in, const float* __restrict__ w,
    const float* __restrict__ b, f16* __restrict__ out, int H) {
  int id = blockIdx.x * 256 + threadIdx.x;
  int total = NB * H * H;
  if (id >= total) return;
  int x = id % H;
  int t = id / H;
  int y = t % H;
  int n = t / H;
  f16* op = out + (size_t)id * MID;
  const float* ip = in + (size_t)n * H * H;
  float p[9];
#pragma unroll
  for (int dy = 0; dy < 3; ++dy)
#pragma unroll
    for (int dx = 0; dx < 3; ++dx) {
      int yy = y + dy - 1, xx = x + dx - 1;
      p[dy * 3 + dx] = (yy >= 0 && yy < H && xx >= 0 && xx < H)
                           ? ip[(size_t)yy * H + xx] : 0.f;
    }
#pragma unroll
  for (int c8 = 0; c8 < 8; ++c8) {
    f16x8 o;
#pragma unroll
    for (int e = 0; e < 8; ++e) {
      int co = c8 * 8 + e;
      float acc = b[co];
#pragma unroll
      for (int k = 0; k < 9; ++k) acc = fmaf(p[k], w[co * 9 + k], acc);
      o[e] = (f16)(acc > 0.f ? acc : 0.01f * acc);
    }
    *(f16x8*)(op + c8 * 8) = o;
  }
}

// ------------------------- conv3: 8 in-ch -> 8 out-ch -----------------------
__global__ __launch_bounds__(256) void csa_conv3_8x8(
    const float* __restrict__ in, const float* __restrict__ w,
    const float* __restrict__ b, float* __restrict__ out, int H, int W) {
  int id = blockIdx.x * 256 + threadIdx.x;
  int total = NB * H * W;
  if (id >= total) return;
  int x = id % W;
  int t = id / W;
  int y = t % H;
  int n = t / H;
  const float* ip = in + (size_t)n * BAND * H * W;
  float p[BAND][9];
#pragma unroll
  for (int ci = 0; ci < BAND; ++ci)
#pragma unroll
    for (int dy = 0; dy < 3; ++dy)
#pragma unroll
      for (int dx = 0; dx < 3; ++dx) {
        int yy = y + dy - 1, xx = x + dx - 1;
        p[ci][dy * 3 + dx] = (yy >= 0 && yy < H && xx >= 0 && xx < W)
                                 ? ip[((size_t)ci * H + yy) * W + xx] : 0.f;
      }
  float* op = out + ((size_t)n * BAND * H + y) * W + x;
  for (int co = 0; co < BAND; ++co) {
    float acc = b[co];
#pragma unroll
    for (int ci = 0; ci < BAND; ++ci)
#pragma unroll
      for (int k = 0; k < 9; ++k)
        acc = fmaf(p[ci][k], w[(co * BAND + ci) * 9 + k], acc);
    acc = acc > 0.f ? acc : 0.01f * acc;
    op[(size_t)co * H * W] = acc;
  }
}

// ---- patches: Kmat[l][(kh,kw,c)] f16 (576 rows), Vt[m][l], norms² ----------
__global__ __launch_bounds__(256) void csa_build_patches(
    const f16* __restrict__ kcl, const float* __restrict__ v_fea,
    f16* __restrict__ Kmat, f16* __restrict__ Vt, float* __restrict__ n2) {
  int blk = blockIdx.x;  // NB*L blocks
  int n = blk / L;
  int l = blk % L;
  int tid = threadIdx.x;
  f16* krow = Kmat + ((size_t)n * L + l) * KDIM;
  int i = l / LN, j = l % LN;
  const f16* kn = kcl + (size_t)n * HK * HK * MID;
  float ss = 0.f;
  for (int ch = tid; ch < 200; ch += 256) {
    int khkw = ch >> 3;
    int c0 = (ch & 7) * 8;
    int kh = khkw / 5, kw = khkw % 5;
    int r = (4 * i + kh + 95) % 97;
    int cc = (4 * j + kw + 95) % 97;
    f16x8 v = {0, 0, 0, 0, 0, 0, 0, 0};
    if (r < HK && cc < HK)
      v = *(const f16x8*)(kn + ((size_t)r * HK + cc) * MID + c0);
#pragma unroll
    for (int e = 0; e < 8; ++e) {
      float fv = (float)v[e];
      ss += fv * fv;
    }
    *(f16x8*)(krow + ch * 8) = v;
  }
  for (int m = tid; m < MV; m += 256) {
    float v = 0.f;
    if (m < VDIM) {
      int kw = m % 5;
      int t = m / 5;
      int kh = t % 5;
      int c = t / 5;
      int r = (4 * i + kh + 95) % 97;
      int cc = (4 * j + kw + 95) % 97;
      v = (r < HK && cc < HK)
              ? v_fea[(((size_t)n * BAND + c) * HK + r) * HK + cc] : 0.f;
    }
    Vt[((size_t)n * MV + m) * L + l] = (f16)v;
  }
  __shared__ float red[256];
  red[tid] = ss;
  __syncthreads();
  for (int s = 128; s > 0; s >>= 1) {
    if (tid < s) red[tid] += red[tid + s];
    __syncthreads();
  }
  if (tid == 0) n2[n * L + l] = red[0];
}

// ---------------- scale[n] = 10 / sqrt(max_l norms2[n][l]) ------------------
__global__ __launch_bounds__(256) void csa_max_scale(
    const float* __restrict__ n2, float* __restrict__ scale) {
  int n = blockIdx.x;
  int tid = threadIdx.x;
  float m = 0.f;
  for (int l = tid; l < L; l += 256) m = fmaxf(m, n2[n * L + l]);
  __shared__ float red[256];
  red[tid] = m;
  __syncthreads();
  for (int s = 128; s > 0; s >>= 1) {
    if (tid < s) red[tid] = fmaxf(red[tid], red[tid + s]);
    __syncthreads();
  }
  if (tid == 0) scale[n] = 10.f / sqrtf(red[0]);
}

// --------------------------- helpers ----------------------------------------
__device__ __forceinline__ void gl_lds16(const f16* g, f16* s) {
  __builtin_amdgcn_global_load_lds(
      (const __attribute__((address_space(1))) void*)g,
      (__attribute__((address_space(3))) void*)s, 16, 0, 0);
}

// --------------------- fused attention kernel -------------------------------
// Block: 32p x full 576l, BK=32, 50 rounds. Staging wave-granular tiles
// (16 rows x 32 k = 1 KB): A tiles 0..1 (qps, coalesced via phase-split),
// B tiles 2..37 (Kmat rows). Wave w computes all 32p x l in [144w,144w+144).
// Softmax exact; e^x f16 -> reused staging LDS [32][PADL]; PV direct Vt.
__global__ __launch_bounds__(256) void csa_attn(
    const f16* __restrict__ qps, const f16* __restrict__ Km,
    const f16* __restrict__ Vt, const float* __restrict__ scale,
    f16* __restrict__ D) {
  __shared__ __attribute__((aligned(16))) f16 shb[19456];  // A|B stage / attn
  __shared__ float mt[4][32], st[4][32], mrow[32], linv[32];

  const int tid = threadIdx.x;
  const int w = tid >> 6;
  const int q = (tid >> 4) & 3;
  const int r = tid & 15;
  const int nb = blockIdx.y;
  const int p0 = blockIdx.x * 32;
  const float sc = scale[nb];
  qps += (size_t)nb * QPSN;
  Km += (size_t)nb * (size_t)L * KDIM;
  Vt += (size_t)nb * (size_t)MV * L;
  D += (size_t)nb * (size_t)MV * PS;

  const int y0 = p0 / 96, x0 = p0 % 96;  // 32 consecutive p share y0 (32|96)

  f32x4 sacc[2][9];
#pragma unroll
  for (int i = 0; i < 2; ++i)
#pragma unroll
    for (int j = 0; j < 9; ++j) {
      f32x4 z = {0.f, 0.f, 0.f, 0.f};
      sacc[i][j] = z;
    }

  // ---------------- QK^T: 50 rounds of BK=32 --------------------------------
  for (int k0 = 0; k0 < KDIM; k0 += 32) {
    const int t32 = k0 >> 5;
    const int half = t32 & 1;
    const int khkw = t32 >> 1;
    const int kh = khkw / 5, kw = khkw % 5;
    // stage 38 tiles round-robin: t = c*4 + w
    const size_t qbase =
        (((size_t)(kw & 3) * HQP + (4 * y0 + kh)) * XI + (x0 + (kw >> 2))) * MID +
        half * 32 + q * 8;
#pragma unroll
    for (int c = 0; c < 10; ++c) {
      const int t = c * 4 + w;
      if (t >= 38) break;
      if (t < 2) {
        gl_lds16(qps + qbase + (size_t)(16 * t + r) * MID, shb + t * 512);
      } else {
        const int b = t - 2;
        gl_lds16(Km + (size_t)(16 * b + r) * KDIM + k0 + q * 8,
                 shb + 1024 + (size_t)b * 512);
      }
    }
    __syncthreads();
    f16x8 af[2];
#pragma unroll
    for (int i = 0; i < 2; ++i)
      af[i] = *(const f16x8*)&shb[i * 512 + q * 128 + r * 8];
#pragma unroll
    for (int j = 0; j < 9; ++j) {
      f16x8 bf = *(const f16x8*)&shb[1024 + (w * 9 + j) * 512 + q * 128 + r * 8];
      sacc[0][j] =
          __builtin_amdgcn_mfma_f32_16x16x32_f16(af[0], bf, sacc[0][j], 0, 0, 0);
      sacc[1][j] =
          __builtin_amdgcn_mfma_f32_16x16x32_f16(af[1], bf, sacc[1][j], 0, 0, 0);
    }
    __syncthreads();
  }

  // ---- exact softmax; lane holds rows 16i+4q+rr, cols l=144w+16j+r ---------
#pragma unroll
  for (int i = 0; i < 2; ++i)
#pragma unroll
    for (int rr = 0; rr < 4; ++rr) {
      float mx = -1e30f;
#pragma unroll
      for (int j = 0; j < 9; ++j) mx = fmaxf(mx, sacc[i][j][rr]);
      mx = fmaxf(mx, __shfl_xor(mx, 1));
      mx = fmaxf(mx, __shfl_xor(mx, 2));
      mx = fmaxf(mx, __shfl_xor(mx, 4));
      mx = fmaxf(mx, __shfl_xor(mx, 8));
      if (r == 0) mt[w][16 * i + 4 * q + rr] = mx;
    }
  __syncthreads();
  if (tid < 32)
    mrow[tid] = fmaxf(fmaxf(mt[0][tid], mt[1][tid]),
                      fmaxf(mt[2][tid], mt[3][tid]));
  __syncthreads();
#pragma unroll
  for (int i = 0; i < 2; ++i)
#pragma unroll
    for (int rr = 0; rr < 4; ++rr) {
      const int pl = 16 * i + 4 * q + rr;
      const float m = mrow[pl];
      float s = 0.f;
#pragma unroll
      for (int j = 0; j < 9; ++j) {
        float e = __expf((sacc[i][j][rr] - m) * sc);
        s += e;
        shb[pl * PADL + 144 * w + 16 * j + r] = (f16)e;
      }
      s += __shfl_xor(s, 1);
      s += __shfl_xor(s, 2);
      s += __shfl_xor(s, 4);
      s += __shfl_xor(s, 8);
      if (r == 0) st[w][pl] = s;
    }
  __syncthreads();
  if (tid < 32)
    linv[tid] = 1.f / (st[0][tid] + st[1][tid] + st[2][tid] + st[3][tid]);
  __syncthreads();

  // ---- PV: D[m][p] = Vt[m][l] x attn[p][l]; wave w owns m [64w, 64w+64) ----
  f32x4 oacc[4][2];
#pragma unroll
  for (int i = 0; i < 4; ++i)
#pragma unroll
    for (int jp = 0; jp < 2; ++jp) {
      f32x4 z = {0.f, 0.f, 0.f, 0.f};
      oacc[i][jp] = z;
    }
  const f16* vb = Vt + (size_t)(64 * w + r) * L + q * 8;
#pragma unroll 1
  for (int rd = 0; rd < 9; ++rd) {
#pragma unroll
    for (int kk = 0; kk < 2; ++kk) {
      const int lo = rd * 64 + kk * 32 + q * 8;
      f16x8 pf0 = *(const f16x8*)&shb[r * PADL + lo];
      f16x8 pf1 = *(const f16x8*)&shb[(16 + r) * PADL + lo];
#pragma unroll
      for (int i = 0; i < 4; ++i) {
        f16x8 vf = *(const f16x8*)(vb + (size_t)(16 * i) * L + rd * 64 + kk * 32);
        oacc[i][0] =
            __builtin_amdgcn_mfma_f32_16x16x32_f16(vf, pf0, oacc[i][0], 0, 0, 0);
        oacc[i][1] =
            __builtin_amdgcn_mfma_f32_16x16x32_f16(vf, pf1, oacc[i][1], 0, 0, 0);
      }
    }
  }
  const float li0 = linv[r], li1 = linv[16 + r];
#pragma unroll
  for (int i = 0; i < 4; ++i)
#pragma unroll
    for (int rr = 0; rr < 4; ++rr) {
      const int m = 64 * w + 16 * i + 4 * q + rr;
      D[(size_t)m * PS + p0 + r] = (f16)(oacc[i][0][rr] * li0);
      D[(size_t)m * PS + p0 + 16 + r] = (f16)(oacc[i][1][rr] * li1);
    }
}

// ------ conv_transpose overlap gather: res[n][co][oy][ox] = sum D / 6 -------
__global__ __launch_bounds__(256) void csa_gather(
    const f16* __restrict__ D, float* __restrict__ res) {
  int id = blockIdx.x * 256 + threadIdx.x;
  if (id >= NB * BAND * HO * HO) return;
  int ox = id % HO;
  int t = id / HO;
  int oy = t % HO;
  t = t / HO;
  int co = t % BAND;
  int n = t / BAND;
  const f16* Dn = D + (size_t)n * MV * PS;
  float s = 0.f;
  int kh0 = oy & 3;
  int kw0 = ox & 3;
  for (int kh = kh0; kh < 5; kh += 4) {
    int y = (oy - kh) >> 2;
    if (y < 0 || y >= 96) continue;
    for (int kw = kw0; kw < 5; kw += 4) {
      int x = (ox - kw) >> 2;
      if (x < 0 || x >= 96) continue;
      s += (float)Dn[(size_t)(co * 25 + kh * 5 + kw) * PS + y * 96 + x];
    }
  }
  res[id] = s * (1.f / 6.f);
}

// ---------------------------------------------------------------------------
extern "C" void kernel_launch(void* const* d_in, const int* in_sizes, int n_in,
                              void* d_out, int out_size, void* d_ws,
                              size_t ws_size, hipStream_t stream) {
  const float* ms   = (const float*)d_in[0];
  const float* pan  = (const float*)d_in[1];
  const float* pan2 = (const float*)d_in[2];
  const float* wq = (const float*)d_in[3];
  const float* bq = (const float*)d_in[4];
  const float* wk = (const float*)d_in[5];
  const float* bk = (const float*)d_in[6];
  const float* wv = (const float*)d_in[7];
  const float* bv = (const float*)d_in[8];
  const float* wr = (const float*)d_in[9];
  const float* br = (const float*)d_in[10];
  float* out = (float*)d_out;

  char* ws = (char*)d_ws;
  f16*   qps   = (f16*)(ws + OFF_QPS);
  f16*   kcl   = (f16*)(ws + OFF_KCL);
  float* v_fea = (float*)(ws + OFF_VFEA);
  float* n2    = (float*)(ws + OFF_N2);
  float* scale = (float*)(ws + OFF_SC);
  f16*   Kmat  = (f16*)(ws + OFF_KM);
  f16*   Vt    = (f16*)(ws + OFF_VT);
  f16*   Dm    = (f16*)(ws + OFF_D);
  float* res   = (float*)(ws + OFF_RES);

  dim3 b256(256);
  csa_convq_ps<<<dim3((NB * 4 * HQP * XI + 255) / 256), b256, 0, stream>>>(
      pan, wq, bq, qps);
  csa_conv_cl<<<dim3((NB * HK * HK + 255) / 256), b256, 0, stream>>>(
      pan2, wk, bk, kcl, HK);
  csa_conv3_8x8<<<dim3((NB * HK * HK + 255) / 256), b256, 0, stream>>>(
      ms, wv, bv, v_fea, HK, HK);
  csa_build_patches<<<dim3(NB * L), b256, 0, stream>>>(kcl, v_fea, Kmat, Vt,
                                                       n2);
  csa_max_scale<<<dim3(NB), b256, 0, stream>>>(n2, scale);

  // fused QK^T + softmax + PV  (576 blocks)
  csa_attn<<<dim3(PS / 32, NB), b256, 0, stream>>>(qps, Kmat, Vt, scale, Dm);

  csa_gather<<<dim3((NB * BAND * HO * HO + 255) / 256), b256, 0, stream>>>(
      Dm, res);
  csa_conv3_8x8<<<dim3((NB * HO * HO + 255) / 256), b256, 0, stream>>>(
      res, wr, br, out, HO, HO);
}